// Round 2
// baseline (157.382 us; speedup 1.0000x reference)
//
#include <hip/hip_runtime.h>
#include <hip/hip_bf16.h>

#define DDIM 448
#define NSTEP 14            // 448 / 32

typedef __hip_bfloat16 bf16;
typedef __attribute__((ext_vector_type(8))) short short8;   // 8 bf16 = 16B (MFMA A/B frag)
typedef __attribute__((ext_vector_type(4))) float f32x4;    // MFMA C/D frag / float4

__device__ __forceinline__ short bf_bits(float f) {
    bf16 h = __float2bfloat16(f);
    return *reinterpret_cast<short*>(&h);
}

// async global->LDS DMA: per-lane 16B; LDS dst = wave-uniform base + lane*16
__device__ __forceinline__ void async16(const bf16* g, bf16* l) {
    __builtin_amdgcn_global_load_lds(
        (const __attribute__((address_space(1))) void*)g,
        (__attribute__((address_space(3))) void*)l, 16, 0, 0);
}

// ---------------------------------------------------------------------------
// Kernel 1: WcT[o][i] = sum_d Wo[d][o] * E[i][d],
//           E[i][d] = Wq[i][d]*diagA[d] + Wk[i][d]*diagB[d] + Wv[i][d]*diagC[d]
// (unchanged — passed, ~5 µs)
// ---------------------------------------------------------------------------
__global__ __launch_bounds__(256) void prep_wc(
    const float* __restrict__ Wq, const float* __restrict__ Wk,
    const float* __restrict__ Wv, const float* __restrict__ Wo,
    const float* __restrict__ Ad, const float* __restrict__ Bd,
    const float* __restrict__ Cd, bf16* __restrict__ WcT)
{
    __shared__ __align__(16) bf16 As[64 * 32];
    __shared__ __align__(16) bf16 Bs[64 * 32];
    __shared__ float da[DDIM], db[DDIM], dc[DDIM];

    const int tid  = threadIdx.x;
    const int i0   = blockIdx.x * 64;
    const int o0   = blockIdx.y * 64;
    const int lane = tid & 63;
    const int wid  = tid >> 6;
    const int wm   = wid >> 1, wn = wid & 1;
    const int m_   = lane & 15, kq = lane >> 4;

    for (int d = tid; d < DDIM; d += 256) {
        da[d] = Ad[d * DDIM + d];
        db[d] = Bd[d * DDIM + d];
        dc[d] = Cd[d * DDIM + d];
    }

    const int dr  = tid >> 3;
    const int oc8 = (tid & 7) * 8;
    const int ir  = tid >> 2;
    const int dc8 = (tid & 3) * 8;

    f32x4 acc[2][2] = {};

    f32x4 w0 = *(const f32x4*)(Wo + dr * DDIM + o0 + oc8);
    f32x4 w1 = *(const f32x4*)(Wo + dr * DDIM + o0 + oc8 + 4);
    f32x4 q0 = *(const f32x4*)(Wq + (i0 + ir) * DDIM + dc8);
    f32x4 q1 = *(const f32x4*)(Wq + (i0 + ir) * DDIM + dc8 + 4);
    f32x4 t0 = *(const f32x4*)(Wk + (i0 + ir) * DDIM + dc8);
    f32x4 t1 = *(const f32x4*)(Wk + (i0 + ir) * DDIM + dc8 + 4);
    f32x4 v0 = *(const f32x4*)(Wv + (i0 + ir) * DDIM + dc8);
    f32x4 v1 = *(const f32x4*)(Wv + (i0 + ir) * DDIM + dc8 + 4);

    for (int k0 = 0; k0 < DDIM; k0 += 32) {
        __syncthreads();
        #pragma unroll
        for (int j = 0; j < 4; ++j) {
            As[(oc8 + j) * 32 + dr]     = __float2bfloat16(w0[j]);
            As[(oc8 + 4 + j) * 32 + dr] = __float2bfloat16(w1[j]);
        }
        short8 e;
        #pragma unroll
        for (int j = 0; j < 4; ++j) {
            e[j]     = bf_bits(q0[j] * da[k0 + dc8 + j]
                             + t0[j] * db[k0 + dc8 + j]
                             + v0[j] * dc[k0 + dc8 + j]);
            e[j + 4] = bf_bits(q1[j] * da[k0 + dc8 + 4 + j]
                             + t1[j] * db[k0 + dc8 + 4 + j]
                             + v1[j] * dc[k0 + dc8 + 4 + j]);
        }
        *(short8*)&Bs[ir * 32 + dc8] = e;
        __syncthreads();

        const int kn = (k0 + 32 < DDIM) ? k0 + 32 : 0;
        w0 = *(const f32x4*)(Wo + (kn + dr) * DDIM + o0 + oc8);
        w1 = *(const f32x4*)(Wo + (kn + dr) * DDIM + o0 + oc8 + 4);
        q0 = *(const f32x4*)(Wq + (i0 + ir) * DDIM + kn + dc8);
        q1 = *(const f32x4*)(Wq + (i0 + ir) * DDIM + kn + dc8 + 4);
        t0 = *(const f32x4*)(Wk + (i0 + ir) * DDIM + kn + dc8);
        t1 = *(const f32x4*)(Wk + (i0 + ir) * DDIM + kn + dc8 + 4);
        v0 = *(const f32x4*)(Wv + (i0 + ir) * DDIM + kn + dc8);
        v1 = *(const f32x4*)(Wv + (i0 + ir) * DDIM + kn + dc8 + 4);

        short8 af[2], bfr[2];
        #pragma unroll
        for (int mi = 0; mi < 2; ++mi)
            af[mi] = *(const short8*)&As[(wm * 32 + mi * 16 + m_) * 32 + kq * 8];
        #pragma unroll
        for (int ni = 0; ni < 2; ++ni)
            bfr[ni] = *(const short8*)&Bs[(wn * 32 + ni * 16 + m_) * 32 + kq * 8];
        #pragma unroll
        for (int mi = 0; mi < 2; ++mi)
            #pragma unroll
            for (int ni = 0; ni < 2; ++ni)
                acc[mi][ni] = __builtin_amdgcn_mfma_f32_16x16x32_bf16(
                    af[mi], bfr[ni], acc[mi][ni], 0, 0, 0);
    }

    #pragma unroll
    for (int mi = 0; mi < 2; ++mi)
        #pragma unroll
        for (int ni = 0; ni < 2; ++ni) {
            const int o = o0 + wm * 32 + mi * 16 + kq * 4;
            const int i = i0 + wn * 32 + ni * 16 + m_;
            #pragma unroll
            for (int r = 0; r < 4; ++r)
                WcT[(o + r) * DDIM + i] = __float2bfloat16(acc[mi][ni][r]);
        }
}

// ---------------------------------------------------------------------------
// Kernel 2: out[M x 448](fp32) = X(fp32) @ Wc    (WcT bf16, o-major, i contig)
// v3: counted-vmcnt pipeline (T3/T4). Same BM=64 double-buffer geometry as
// v2 (LDS 64 KB, 2 blocks/CU), but the per-step __syncthreads() (which
// compiled to s_waitcnt vmcnt(0) — draining the X HBM prefetch EVERY step)
// is replaced by:
//   loop top:  s_waitcnt vmcnt(2)   — in-order vmcnt retire => the 7 B-DMAs
//              (oldest) are done; the 2 newer X loads stay in flight.
//   loop end:  s_waitcnt lgkmcnt(0); raw s_barrier — A-tile visibility only.
// B is per-wave self-consistent (wave w DMAs and reads exactly rows
// [w*112, w*112+112)), so own-wave vmcnt ordering suffices; no cross-wave
// vmem ordering needed. sched_barrier(0) pins VMEM issue order
// (B-DMAs before X prefetch) so the vmcnt count is exact. Last step has no
// trailing X loads => vmcnt(0) there.
// Epilogue: Cb padded to stride 452 f32 (kq-groups 16 banks apart -> 2-way
// = free, was 4-way at stride 448), 4 stages x 16 rows; raw lgkm barriers
// (no vmcnt drain of the global stores).
// smem: A0 @0 (4K), A1 @4K (4K), B0 @8K (28K), B1 @36K (28K) = 64 KB;
// Cb @8K: 16x452x4 = 28.9 KB (aliases B — safe after loop-end barrier).
// ---------------------------------------------------------------------------
__global__ __launch_bounds__(256, 2) void gemm_xwc(
    const float* __restrict__ X, const bf16* __restrict__ WcT,
    float* __restrict__ out)
{
    __shared__ __align__(16) char smem[65536];          // 64 KB

    const int tid  = threadIdx.x;
    const int lane = tid & 63;
    const int wid  = tid >> 6;               // col quarter: 112 cols
    const int m_   = lane & 15;
    const int kq   = lane >> 4;
    const int row0 = blockIdx.x * 64;

    // A staging: 64x32 fp32 -> 8 elem/thread
    const int ar = tid >> 2;                 // 0..63
    const int ac = (tid & 3) * 8;            // 0,8,16,24
    const float* agp = X + (row0 + ar) * DDIM + ac;

    // B DMA lane map: instr j covers rows (wid*7+j)*16 + lrow, 64B per row
    const int lrow = lane >> 2;
    const int lcol = (lane & 3) * 8;
    const bf16* bgp = WcT + (wid * 112 + lrow) * DDIM + lcol;

    f32x4 acc[4][7] = {};

    // ---- prologue. VMEM issue order (pinned by sched_barrier):
    //   [X k=0 loads] | [7 B-DMAs] | [stage A(0) (waits X k=0), X k=32 loads]
    // => entering loop: outstanding = 7 DMA (oldest) + 2 X k=32 (newest).
    f32x4 a0 = *(const f32x4*)(agp);
    f32x4 a1 = *(const f32x4*)(agp + 4);
    __builtin_amdgcn_sched_barrier(0);
    {
        bf16* B0 = (bf16*)(smem + 8192);
        #pragma unroll
        for (int j = 0; j < 7; ++j)
            async16(bgp + j * 16 * DDIM, B0 + (wid * 7 + j) * 16 * 32);
    }
    __builtin_amdgcn_sched_barrier(0);
    {
        bf16* A0 = (bf16*)smem;
        short8 w;
        #pragma unroll
        for (int j = 0; j < 4; ++j) {
            w[j] = bf_bits(a0[j]); w[j + 4] = bf_bits(a1[j]);
        }
        *(short8*)&A0[ar * 32 + ac] = w;     // byte addr = tid*16: conflict-free
    }
    a0 = *(const f32x4*)(agp + 32);
    a1 = *(const f32x4*)(agp + 36);
    asm volatile("s_waitcnt lgkmcnt(0)" ::: "memory");
    __builtin_amdgcn_s_barrier();            // A(0) visible; DMAs stay in flight

    for (int s = 0; s < NSTEP; ++s) {
        const int cur = s & 1, nxt = cur ^ 1;
        const bf16* Ac = (const bf16*)(smem + (cur << 12));          // 0 / 4K
        const bf16* Bc = (const bf16*)(smem + 8192 + cur * 28672);   // 8K / 36K

        // B(cur) DMAs are the 7 oldest outstanding vmem ops; the 2 newer
        // X prefetch loads may remain in flight (in-order vmcnt retire).
        if (s + 1 < NSTEP) {                  // uniform, unrolled away
            asm volatile("s_waitcnt vmcnt(2)" ::: "memory");
        } else {
            asm volatile("s_waitcnt vmcnt(0)" ::: "memory");
        }

        short8 af[4], bfr[7];
        #pragma unroll
        for (int mi = 0; mi < 4; ++mi)
            af[mi] = *(const short8*)&Ac[(mi * 16 + m_) * 32 + kq * 8];
        #pragma unroll
        for (int ni = 0; ni < 7; ++ni)
            bfr[ni] = *(const short8*)&Bc[(wid * 112 + ni * 16 + m_) * 32 + kq * 8];

        if (s + 1 < NSTEP) {                  // uniform
            bf16* An = (bf16*)(smem + (nxt << 12));
            bf16* Bn = (bf16*)(smem + 8192 + nxt * 28672);
            // stage A(next) from regs (hold k=(s+1)*32; compiler inserts the
            // precise vmcnt wait for these a-regs itself)
            short8 w;
            #pragma unroll
            for (int j = 0; j < 4; ++j) {
                w[j] = bf_bits(a0[j]); w[j + 4] = bf_bits(a1[j]);
            }
            *(short8*)&An[ar * 32 + ac] = w;
            // DMA B(next)
            const int kn = (s + 1) * 32;
            #pragma unroll
            for (int j = 0; j < 7; ++j)
                async16(bgp + j * 16 * DDIM + kn, Bn + (wid * 7 + j) * 16 * 32);
            // pin issue order: all B-DMAs before the X prefetch loads,
            // so next step's vmcnt(2) counts exactly the 2 X loads.
            __builtin_amdgcn_sched_barrier(0);
            if (s + 2 < NSTEP) {              // uniform
                const int k2 = (s + 2) * 32;
                a0 = *(const f32x4*)(agp + k2);
                a1 = *(const f32x4*)(agp + k2 + 4);
            }
        }

        #pragma unroll
        for (int mi = 0; mi < 4; ++mi)
            #pragma unroll
            for (int ni = 0; ni < 7; ++ni)
                acc[mi][ni] = __builtin_amdgcn_mfma_f32_16x16x32_bf16(
                    af[mi], bfr[ni], acc[mi][ni], 0, 0, 0);

        // A(next) ds_writes visible + all cur reads done; B-DMAs for next
        // step (and X loads) remain in flight across the barrier.
        asm volatile("s_waitcnt lgkmcnt(0)" ::: "memory");
        __builtin_amdgcn_s_barrier();
    }

    // ---- epilogue: 4 stages of 16 rows; padded LDS bounce (stride 452)
    float* Cb = (float*)(smem + 8192);        // 16x452 fp32 = 28.9 KB
    const int erow = tid >> 4;                // 0..15
    const int ec0  = tid & 15;
    #pragma unroll
    for (int t = 0; t < 4; ++t) {
        #pragma unroll
        for (int ni = 0; ni < 7; ++ni) {
            const int col = wid * 112 + ni * 16 + m_;
            #pragma unroll
            for (int r = 0; r < 4; ++r)
                Cb[(kq * 4 + r) * 452 + col] = acc[t][ni][r];
        }
        asm volatile("s_waitcnt lgkmcnt(0)" ::: "memory");
        __builtin_amdgcn_s_barrier();
        float* dst = out + (row0 + t * 16) * DDIM;
        #pragma unroll
        for (int j = 0; j < 7; ++j)
            *(f32x4*)(dst + erow * DDIM + (ec0 + j * 16) * 4) =
                *(const f32x4*)(Cb + erow * 452 + (ec0 + j * 16) * 4);
        asm volatile("s_waitcnt lgkmcnt(0)" ::: "memory");
        __builtin_amdgcn_s_barrier();         // before next stage overwrites Cb
    }
}

// ---------------------------------------------------------------------------
extern "C" void kernel_launch(void* const* d_in, const int* in_sizes, int n_in,
                              void* d_out, int out_size, void* d_ws, size_t ws_size,
                              hipStream_t stream) {
    const float* x  = (const float*)d_in[0];
    const float* Wq = (const float*)d_in[1];
    const float* Wk = (const float*)d_in[2];
    const float* Wv = (const float*)d_in[3];
    const float* Wo = (const float*)d_in[4];
    const float* Ad = (const float*)d_in[5];
    const float* Bd = (const float*)d_in[6];
    const float* Cd = (const float*)d_in[7];

    bf16*  WcT = (bf16*)d_ws;                      // 448*448*2 = 392 KiB scratch
    float* out = (float*)d_out;

    const int M = in_sizes[0] / DDIM;              // 32768

    prep_wc<<<dim3(7, 7), 256, 0, stream>>>(Wq, Wk, Wv, Wo, Ad, Bd, Cd, WcT);
    gemm_xwc<<<M / 64, 256, 0, stream>>>(x, WcT, out);
}

// Round 3
// 145.148 us; speedup vs baseline: 1.0843x; 1.0843x over previous
//
#include <hip/hip_runtime.h>
#include <hip/hip_bf16.h>

#define DDIM 448
#define NSTEP 14            // 448 / 32

typedef __hip_bfloat16 bf16;
typedef __attribute__((ext_vector_type(8))) short short8;   // 8 bf16 = 16B (MFMA A/B frag)
typedef __attribute__((ext_vector_type(4))) float f32x4;    // MFMA C/D frag / float4

__device__ __forceinline__ short bf_bits(float f) {
    bf16 h = __float2bfloat16(f);
    return *reinterpret_cast<short*>(&h);
}

// async global->LDS DMA: per-lane 16B; LDS dst = wave-uniform base + lane*16
__device__ __forceinline__ void async16(const bf16* g, bf16* l) {
    __builtin_amdgcn_global_load_lds(
        (const __attribute__((address_space(1))) void*)g,
        (__attribute__((address_space(3))) void*)l, 16, 0, 0);
}

// ---------------------------------------------------------------------------
// Kernel 1: fused weight  E[i][d] = Wq*diagA + Wk*diagB + Wv*diagC,
//           Wc[i][o] = sum_d E[i][d] * Wo[d][o].
// v4 change: OUTPUT LAYOUT. Instead of WcT[o][i] (row stride 896B, which
// made the GEMM's B-DMA a 16-line gather per instruction), write the GEMM's
// exact LDS image: Wt[s][o][k] = Wc[s*32+k][o], s = K-step, o in [0,448),
// k in [0,32). Each K-step slab is 448*32*2 = 28 KB contiguous, so the
// GEMM's global_load_lds reads are 1 KB linear (8 full lines, sequential).
// ---------------------------------------------------------------------------
__global__ __launch_bounds__(256) void prep_wc(
    const float* __restrict__ Wq, const float* __restrict__ Wk,
    const float* __restrict__ Wv, const float* __restrict__ Wo,
    const float* __restrict__ Ad, const float* __restrict__ Bd,
    const float* __restrict__ Cd, bf16* __restrict__ Wt)
{
    __shared__ __align__(16) bf16 As[64 * 32];
    __shared__ __align__(16) bf16 Bs[64 * 32];
    __shared__ float da[DDIM], db[DDIM], dc[DDIM];

    const int tid  = threadIdx.x;
    const int i0   = blockIdx.x * 64;
    const int o0   = blockIdx.y * 64;
    const int lane = tid & 63;
    const int wid  = tid >> 6;
    const int wm   = wid >> 1, wn = wid & 1;
    const int m_   = lane & 15, kq = lane >> 4;

    for (int d = tid; d < DDIM; d += 256) {
        da[d] = Ad[d * DDIM + d];
        db[d] = Bd[d * DDIM + d];
        dc[d] = Cd[d * DDIM + d];
    }

    const int dr  = tid >> 3;
    const int oc8 = (tid & 7) * 8;
    const int ir  = tid >> 2;
    const int dc8 = (tid & 3) * 8;

    f32x4 acc[2][2] = {};

    f32x4 w0 = *(const f32x4*)(Wo + dr * DDIM + o0 + oc8);
    f32x4 w1 = *(const f32x4*)(Wo + dr * DDIM + o0 + oc8 + 4);
    f32x4 q0 = *(const f32x4*)(Wq + (i0 + ir) * DDIM + dc8);
    f32x4 q1 = *(const f32x4*)(Wq + (i0 + ir) * DDIM + dc8 + 4);
    f32x4 t0 = *(const f32x4*)(Wk + (i0 + ir) * DDIM + dc8);
    f32x4 t1 = *(const f32x4*)(Wk + (i0 + ir) * DDIM + dc8 + 4);
    f32x4 v0 = *(const f32x4*)(Wv + (i0 + ir) * DDIM + dc8);
    f32x4 v1 = *(const f32x4*)(Wv + (i0 + ir) * DDIM + dc8 + 4);

    for (int k0 = 0; k0 < DDIM; k0 += 32) {
        __syncthreads();
        #pragma unroll
        for (int j = 0; j < 4; ++j) {
            As[(oc8 + j) * 32 + dr]     = __float2bfloat16(w0[j]);
            As[(oc8 + 4 + j) * 32 + dr] = __float2bfloat16(w1[j]);
        }
        short8 e;
        #pragma unroll
        for (int j = 0; j < 4; ++j) {
            e[j]     = bf_bits(q0[j] * da[k0 + dc8 + j]
                             + t0[j] * db[k0 + dc8 + j]
                             + v0[j] * dc[k0 + dc8 + j]);
            e[j + 4] = bf_bits(q1[j] * da[k0 + dc8 + 4 + j]
                             + t1[j] * db[k0 + dc8 + 4 + j]
                             + v1[j] * dc[k0 + dc8 + 4 + j]);
        }
        *(short8*)&Bs[ir * 32 + dc8] = e;
        __syncthreads();

        const int kn = (k0 + 32 < DDIM) ? k0 + 32 : 0;
        w0 = *(const f32x4*)(Wo + (kn + dr) * DDIM + o0 + oc8);
        w1 = *(const f32x4*)(Wo + (kn + dr) * DDIM + o0 + oc8 + 4);
        q0 = *(const f32x4*)(Wq + (i0 + ir) * DDIM + kn + dc8);
        q1 = *(const f32x4*)(Wq + (i0 + ir) * DDIM + kn + dc8 + 4);
        t0 = *(const f32x4*)(Wk + (i0 + ir) * DDIM + kn + dc8);
        t1 = *(const f32x4*)(Wk + (i0 + ir) * DDIM + kn + dc8 + 4);
        v0 = *(const f32x4*)(Wv + (i0 + ir) * DDIM + kn + dc8);
        v1 = *(const f32x4*)(Wv + (i0 + ir) * DDIM + kn + dc8 + 4);

        short8 af[2], bfr[2];
        #pragma unroll
        for (int mi = 0; mi < 2; ++mi)
            af[mi] = *(const short8*)&As[(wm * 32 + mi * 16 + m_) * 32 + kq * 8];
        #pragma unroll
        for (int ni = 0; ni < 2; ++ni)
            bfr[ni] = *(const short8*)&Bs[(wn * 32 + ni * 16 + m_) * 32 + kq * 8];
        #pragma unroll
        for (int mi = 0; mi < 2; ++mi)
            #pragma unroll
            for (int ni = 0; ni < 2; ++ni)
                acc[mi][ni] = __builtin_amdgcn_mfma_f32_16x16x32_bf16(
                    af[mi], bfr[ni], acc[mi][ni], 0, 0, 0);
    }

    // acc[mi][ni][r] = Wc[i][o+r-ish]: o index = o0+wm*32+mi*16+kq*4+r (row of
    // WcT), i index = i0+wn*32+ni*16+m_ (k dim). Write tiled: Wt[s][o][i&31].
    #pragma unroll
    for (int mi = 0; mi < 2; ++mi)
        #pragma unroll
        for (int ni = 0; ni < 2; ++ni) {
            const int o = o0 + wm * 32 + mi * 16 + kq * 4;
            const int i = i0 + wn * 32 + ni * 16 + m_;
            bf16* dst = Wt + (i >> 5) * (DDIM * 32) + (i & 31);
            #pragma unroll
            for (int r = 0; r < 4; ++r)
                dst[(o + r) * 32] = __float2bfloat16(acc[mi][ni][r]);
        }
}

// ---------------------------------------------------------------------------
// Kernel 2: out[M x 448](fp32) = X(fp32) @ Wc.  B supplied as Wt[s][o][k]
// (GEMM LDS image order, 28 KB contiguous per K-step).
// v4 = the proven v1 structure (BM=128, 256 blocks = 1/CU, 4 waves, both
// A and B double-buffered, ONE plain __syncthreads per K-step — no asm,
// no sched_barrier; R2 proved those regress) with two changes:
//   1. B-DMA is now LINEAR: async16 j moves 1 KB contiguous (8 full lines,
//      sequential) instead of a 16-line stride-896B gather. Theory: the
//      per-step vmcnt drain was waiting on ~450 scattered line-gathers per
//      CU; linear streams halve the line count and pipeline in L2.
//   2. Epilogue bounce padded to stride 452 f32 (448%32==0 made the kq
//      write groups a 4-way bank conflict; 452 -> 2-way = free).
// smem: A0 @0 (8K), A1 @8K (8K), B0 @16K (28K), B1 @44K (28K);
// epilogue Cb @16K: 32 x 452 x 4B = 56.5 KB (aliases B). Total 74240 B.
// ---------------------------------------------------------------------------
__global__ __launch_bounds__(256, 1) void gemm_xwc(
    const float* __restrict__ X, const bf16* __restrict__ Wt,
    float* __restrict__ out)
{
    __shared__ __align__(16) char smem[74240];

    const int tid  = threadIdx.x;
    const int lane = tid & 63;
    const int wid  = tid >> 6;               // col quarter: 112 cols
    const int m_   = lane & 15;
    const int kq   = lane >> 4;
    const int row0 = blockIdx.x * 128;

    // A staging: 128x32 fp32 -> 16 elem/thread
    const int ar = tid >> 1;                 // 0..127
    const int ac = (tid & 1) * 16;           // 0 or 16
    const float* agp = X + (row0 + ar) * DDIM + ac;

    // B DMA: linear. Wave wid, instr j covers Wt-slab bytes
    // [(wid*7+j)*1024, +1024) of K-step s; per-lane src offset = lane*16B.
    const bf16* bgp = Wt + wid * 7 * 512 + lane * 8;     // elems (512 bf16 = 1KB)

    f32x4 acc[8][7] = {};

    // ---- prologue: DMA B(0); load+stage A(0); prefetch a-regs for k=32
    {
        bf16* B0 = (bf16*)(smem + 16384);
        #pragma unroll
        for (int j = 0; j < 7; ++j)
            async16(bgp + j * 512, B0 + (wid * 7 + j) * 512);
    }

    f32x4 a0 = *(const f32x4*)(agp);
    f32x4 a1 = *(const f32x4*)(agp + 4);
    f32x4 a2 = *(const f32x4*)(agp + 8);
    f32x4 a3 = *(const f32x4*)(agp + 12);
    {
        bf16* A0 = (bf16*)smem;
        short8 w0, w1;
        #pragma unroll
        for (int j = 0; j < 4; ++j) {
            w0[j] = bf_bits(a0[j]); w0[j + 4] = bf_bits(a1[j]);
            w1[j] = bf_bits(a2[j]); w1[j + 4] = bf_bits(a3[j]);
        }
        *(short8*)&A0[ar * 32 + ac]     = w0;
        *(short8*)&A0[ar * 32 + ac + 8] = w1;
    }
    a0 = *(const f32x4*)(agp + 32);
    a1 = *(const f32x4*)(agp + 36);
    a2 = *(const f32x4*)(agp + 40);
    a3 = *(const f32x4*)(agp + 44);
    __syncthreads();                          // drains DMA(0), A(0) writes

    for (int s = 0; s < NSTEP; ++s) {
        const int cur = s & 1, nxt = cur ^ 1;
        const bf16* Ac = (const bf16*)(smem + (cur << 13));           // 0 / 8K
        const bf16* Bc = (const bf16*)(smem + 16384 + cur * 28672);   // 16K / 44K

        if (s + 1 < NSTEP) {                  // uniform
            bf16* An = (bf16*)(smem + (nxt << 13));
            bf16* Bn = (bf16*)(smem + 16384 + nxt * 28672);
            // stage A(next) from regs (hold k=(s+1)*32)
            short8 w0, w1;
            #pragma unroll
            for (int j = 0; j < 4; ++j) {
                w0[j] = bf_bits(a0[j]); w0[j + 4] = bf_bits(a1[j]);
                w1[j] = bf_bits(a2[j]); w1[j + 4] = bf_bits(a3[j]);
            }
            *(short8*)&An[ar * 32 + ac]     = w0;
            *(short8*)&An[ar * 32 + ac + 8] = w1;
            // DMA B(next): linear 1KB per instr from the (s+1) slab
            const bf16* bsrc = bgp + (s + 1) * (DDIM * 32);
            #pragma unroll
            for (int j = 0; j < 7; ++j)
                async16(bsrc + j * 512, Bn + (wid * 7 + j) * 512);
            // prefetch a-regs for k=(s+2)*32
            if (s + 2 < NSTEP) {              // uniform
                const int k2 = (s + 2) * 32;
                a0 = *(const f32x4*)(agp + k2);
                a1 = *(const f32x4*)(agp + k2 + 4);
                a2 = *(const f32x4*)(agp + k2 + 8);
                a3 = *(const f32x4*)(agp + k2 + 12);
            }
        }

        short8 af[8], bfr[7];
        #pragma unroll
        for (int mi = 0; mi < 8; ++mi)
            af[mi] = *(const short8*)&Ac[(mi * 16 + m_) * 32 + kq * 8];
        #pragma unroll
        for (int ni = 0; ni < 7; ++ni)
            bfr[ni] = *(const short8*)&Bc[(wid * 112 + ni * 16 + m_) * 32 + kq * 8];

        #pragma unroll
        for (int mi = 0; mi < 8; ++mi)
            #pragma unroll
            for (int ni = 0; ni < 7; ++ni)
                acc[mi][ni] = __builtin_amdgcn_mfma_f32_16x16x32_bf16(
                    af[mi], bfr[ni], acc[mi][ni], 0, 0, 0);

        __syncthreads();   // cur fully read; next buffers + vmem drained
    }

    // ---- epilogue: 4 stages of 32 rows; padded LDS bounce (stride 452 f32)
    float* Cb = (float*)(smem + 16384);       // 32 x 452 fp32
    #pragma unroll
    for (int t = 0; t < 4; ++t) {
        #pragma unroll
        for (int mi2 = 0; mi2 < 2; ++mi2) {
            const int mi = t * 2 + mi2;
            #pragma unroll
            for (int ni = 0; ni < 7; ++ni) {
                const int col = wid * 112 + ni * 16 + m_;
                #pragma unroll
                for (int r = 0; r < 4; ++r)
                    Cb[(mi2 * 16 + kq * 4 + r) * 452 + col] = acc[mi][ni][r];
            }
        }
        __syncthreads();
        // flat coalesced readout: 32x448 f32 = 3584 vec4 = 14 x 256
        const f32x4* Cb4 = (const f32x4*)Cb;
        f32x4* dst4 = (f32x4*)(out + (row0 + t * 32) * DDIM);
        #pragma unroll
        for (int j = 0; j < 14; ++j) {
            const int v   = j * 256 + tid;
            const int row = v / 112;          // 112 vec4 per output row
            const int cw  = v - row * 112;
            dst4[v] = Cb4[row * 113 + cw];    // 113 vec4 = 452 f32 stride
        }
        __syncthreads();   // before next stage overwrites Cb
    }
}

// ---------------------------------------------------------------------------
extern "C" void kernel_launch(void* const* d_in, const int* in_sizes, int n_in,
                              void* d_out, int out_size, void* d_ws, size_t ws_size,
                              hipStream_t stream) {
    const float* x  = (const float*)d_in[0];
    const float* Wq = (const float*)d_in[1];
    const float* Wk = (const float*)d_in[2];
    const float* Wv = (const float*)d_in[3];
    const float* Wo = (const float*)d_in[4];
    const float* Ad = (const float*)d_in[5];
    const float* Bd = (const float*)d_in[6];
    const float* Cd = (const float*)d_in[7];

    bf16*  Wt  = (bf16*)d_ws;                      // 448*448*2 = 392 KiB scratch
    float* out = (float*)d_out;

    const int M = in_sizes[0] / DDIM;              // 32768

    prep_wc<<<dim3(7, 7), 256, 0, stream>>>(Wq, Wk, Wv, Wo, Ad, Bd, Cd, Wt);
    gemm_xwc<<<M / 128, 256, 0, stream>>>(x, Wt, out);
}

// Round 4
// 142.803 us; speedup vs baseline: 1.1021x; 1.0164x over previous
//
#include <hip/hip_runtime.h>
#include <hip/hip_bf16.h>

#define DDIM 448
#define NSTEP 14            // 448 / 32

typedef __hip_bfloat16 bf16;
typedef __attribute__((ext_vector_type(8))) short short8;   // 8 bf16 = 16B (MFMA A/B frag)
typedef __attribute__((ext_vector_type(4))) float f32x4;    // MFMA C/D frag / float4

__device__ __forceinline__ short bf_bits(float f) {
    bf16 h = __float2bfloat16(f);
    return *reinterpret_cast<short*>(&h);
}

// async global->LDS DMA: per-lane 16B; LDS dst = wave-uniform base + lane*16
__device__ __forceinline__ void async16(const bf16* g, bf16* l) {
    __builtin_amdgcn_global_load_lds(
        (const __attribute__((address_space(1))) void*)g,
        (__attribute__((address_space(3))) void*)l, 16, 0, 0);
}

// ---------------------------------------------------------------------------
// Kernel 1: fused weight  E[i][d] = Wq*diagA + Wk*diagB + Wv*diagC,
//           Wc[i][o] = sum_d E[i][d] * Wo[d][o].
// Output layout (v4, verified): Wt[s][o][k] = Wc[s*32+k][o] — the GEMM's
// exact LDS image; each K-step slab is 448*32*2 = 28 KB contiguous so the
// GEMM's global_load_lds reads are 1 KB linear.  UNCHANGED from R3.
// ---------------------------------------------------------------------------
__global__ __launch_bounds__(256) void prep_wc(
    const float* __restrict__ Wq, const float* __restrict__ Wk,
    const float* __restrict__ Wv, const float* __restrict__ Wo,
    const float* __restrict__ Ad, const float* __restrict__ Bd,
    const float* __restrict__ Cd, bf16* __restrict__ Wt)
{
    __shared__ __align__(16) bf16 As[64 * 32];
    __shared__ __align__(16) bf16 Bs[64 * 32];
    __shared__ float da[DDIM], db[DDIM], dc[DDIM];

    const int tid  = threadIdx.x;
    const int i0   = blockIdx.x * 64;
    const int o0   = blockIdx.y * 64;
    const int lane = tid & 63;
    const int wid  = tid >> 6;
    const int wm   = wid >> 1, wn = wid & 1;
    const int m_   = lane & 15, kq = lane >> 4;

    for (int d = tid; d < DDIM; d += 256) {
        da[d] = Ad[d * DDIM + d];
        db[d] = Bd[d * DDIM + d];
        dc[d] = Cd[d * DDIM + d];
    }

    const int dr  = tid >> 3;
    const int oc8 = (tid & 7) * 8;
    const int ir  = tid >> 2;
    const int dc8 = (tid & 3) * 8;

    f32x4 acc[2][2] = {};

    f32x4 w0 = *(const f32x4*)(Wo + dr * DDIM + o0 + oc8);
    f32x4 w1 = *(const f32x4*)(Wo + dr * DDIM + o0 + oc8 + 4);
    f32x4 q0 = *(const f32x4*)(Wq + (i0 + ir) * DDIM + dc8);
    f32x4 q1 = *(const f32x4*)(Wq + (i0 + ir) * DDIM + dc8 + 4);
    f32x4 t0 = *(const f32x4*)(Wk + (i0 + ir) * DDIM + dc8);
    f32x4 t1 = *(const f32x4*)(Wk + (i0 + ir) * DDIM + dc8 + 4);
    f32x4 v0 = *(const f32x4*)(Wv + (i0 + ir) * DDIM + dc8);
    f32x4 v1 = *(const f32x4*)(Wv + (i0 + ir) * DDIM + dc8 + 4);

    for (int k0 = 0; k0 < DDIM; k0 += 32) {
        __syncthreads();
        #pragma unroll
        for (int j = 0; j < 4; ++j) {
            As[(oc8 + j) * 32 + dr]     = __float2bfloat16(w0[j]);
            As[(oc8 + 4 + j) * 32 + dr] = __float2bfloat16(w1[j]);
        }
        short8 e;
        #pragma unroll
        for (int j = 0; j < 4; ++j) {
            e[j]     = bf_bits(q0[j] * da[k0 + dc8 + j]
                             + t0[j] * db[k0 + dc8 + j]
                             + v0[j] * dc[k0 + dc8 + j]);
            e[j + 4] = bf_bits(q1[j] * da[k0 + dc8 + 4 + j]
                             + t1[j] * db[k0 + dc8 + 4 + j]
                             + v1[j] * dc[k0 + dc8 + 4 + j]);
        }
        *(short8*)&Bs[ir * 32 + dc8] = e;
        __syncthreads();

        const int kn = (k0 + 32 < DDIM) ? k0 + 32 : 0;
        w0 = *(const f32x4*)(Wo + (kn + dr) * DDIM + o0 + oc8);
        w1 = *(const f32x4*)(Wo + (kn + dr) * DDIM + o0 + oc8 + 4);
        q0 = *(const f32x4*)(Wq + (i0 + ir) * DDIM + kn + dc8);
        q1 = *(const f32x4*)(Wq + (i0 + ir) * DDIM + kn + dc8 + 4);
        t0 = *(const f32x4*)(Wk + (i0 + ir) * DDIM + kn + dc8);
        t1 = *(const f32x4*)(Wk + (i0 + ir) * DDIM + kn + dc8 + 4);
        v0 = *(const f32x4*)(Wv + (i0 + ir) * DDIM + kn + dc8);
        v1 = *(const f32x4*)(Wv + (i0 + ir) * DDIM + kn + dc8 + 4);

        short8 af[2], bfr[2];
        #pragma unroll
        for (int mi = 0; mi < 2; ++mi)
            af[mi] = *(const short8*)&As[(wm * 32 + mi * 16 + m_) * 32 + kq * 8];
        #pragma unroll
        for (int ni = 0; ni < 2; ++ni)
            bfr[ni] = *(const short8*)&Bs[(wn * 32 + ni * 16 + m_) * 32 + kq * 8];
        #pragma unroll
        for (int mi = 0; mi < 2; ++mi)
            #pragma unroll
            for (int ni = 0; ni < 2; ++ni)
                acc[mi][ni] = __builtin_amdgcn_mfma_f32_16x16x32_bf16(
                    af[mi], bfr[ni], acc[mi][ni], 0, 0, 0);
    }

    #pragma unroll
    for (int mi = 0; mi < 2; ++mi)
        #pragma unroll
        for (int ni = 0; ni < 2; ++ni) {
            const int o = o0 + wm * 32 + mi * 16 + kq * 4;
            const int i = i0 + wn * 32 + ni * 16 + m_;
            bf16* dst = Wt + (i >> 5) * (DDIM * 32) + (i & 31);
            #pragma unroll
            for (int r = 0; r < 4; ++r)
                dst[(o + r) * 32] = __float2bfloat16(acc[mi][ni][r]);
        }
}

// ---------------------------------------------------------------------------
// Kernel 2: out[M x 448](fp32) = X(fp32) @ Wc.  B supplied as Wt[s][o][k].
// v5: SAME 128x448 tile, double-buffering, linear 1KB B-DMA and one plain
// __syncthreads per K-step as the verified v4 — but 512 threads / 8 waves
// (was 256/4). v4 had exactly ONE wave per SIMD, so every lgkm chain and
// the per-step vmcnt(0) barrier-drain of the X prefetch was 100% exposed
// (counters: MfmaUtil 10, VALUBusy 5, HBM 26% — all idle = latency-bound).
// Wave (wr,wc) = (wid>>2, wid&3) owns a 64x112 sub-tile: acc[4][7] =
// 112 VGPR -> ~170 total -> 2 waves/SIMD (__launch_bounds__(512,2)).
// While one wave sits in the drain, its SIMD-mate issues MFMAs.
// Per-SIMD MFMA/step unchanged (56); B-frag LDS reads double (fine vs
// 256 B/cy). DMA still 28 KB/step issued by waves 0-3.
// smem: A0 @0 (8K), A1 @8K, B0 @16K (28K), B1 @44K (28K);
// epilogue Cb @16K: 32 x 452 x 4B = 57856 B (aliases B). Total 74240 B.
// ---------------------------------------------------------------------------
__global__ __launch_bounds__(512, 2) void gemm_xwc(
    const float* __restrict__ X, const bf16* __restrict__ Wt,
    float* __restrict__ out)
{
    __shared__ __align__(16) char smem[74240];

    const int tid  = threadIdx.x;
    const int lane = tid & 63;
    const int wid  = tid >> 6;               // 0..7
    const int wr   = wid >> 2;               // row half: rows wr*64 + [0,64)
    const int wc   = wid & 3;                // col quarter: cols wc*112 + [0,112)
    const int m_   = lane & 15;
    const int kq   = lane >> 4;
    const int row0 = blockIdx.x * 128;

    // A staging: 128x32 fp32 -> 8 f32/thread
    const int ar = tid >> 2;                 // 0..127
    const int ac = (tid & 3) * 8;            // 0,8,16,24
    const float* agp = X + (row0 + ar) * DDIM + ac;

    // B DMA (waves 0-3): instr j moves 1 KB linear from the Wt slab
    const bf16* bgp = Wt + wc * 7 * 512 + lane * 8;

    f32x4 acc[4][7] = {};

    // ---- prologue: DMA B(0); load+stage A(0); prefetch a-regs for k=32
    {
        bf16* B0 = (bf16*)(smem + 16384);
        if (wid < 4) {
            #pragma unroll
            for (int j = 0; j < 7; ++j)
                async16(bgp + j * 512, B0 + (wc * 7 + j) * 512);
        }
    }

    f32x4 a0 = *(const f32x4*)(agp);
    f32x4 a1 = *(const f32x4*)(agp + 4);
    {
        bf16* A0 = (bf16*)smem;
        short8 w;
        #pragma unroll
        for (int j = 0; j < 4; ++j) {
            w[j] = bf_bits(a0[j]); w[j + 4] = bf_bits(a1[j]);
        }
        *(short8*)&A0[ar * 32 + ac] = w;     // byte addr = tid*16
    }
    a0 = *(const f32x4*)(agp + 32);
    a1 = *(const f32x4*)(agp + 36);
    __syncthreads();                          // drains DMA(0), A(0) writes

    for (int s = 0; s < NSTEP; ++s) {
        const int cur = s & 1, nxt = cur ^ 1;
        const bf16* Ac = (const bf16*)(smem + (cur << 13));           // 0 / 8K
        const bf16* Bc = (const bf16*)(smem + 16384 + cur * 28672);   // 16K / 44K

        if (s + 1 < NSTEP) {                  // uniform
            bf16* An = (bf16*)(smem + (nxt << 13));
            bf16* Bn = (bf16*)(smem + 16384 + nxt * 28672);
            // stage A(next) from regs (hold k=(s+1)*32)
            short8 w;
            #pragma unroll
            for (int j = 0; j < 4; ++j) {
                w[j] = bf_bits(a0[j]); w[j + 4] = bf_bits(a1[j]);
            }
            *(short8*)&An[ar * 32 + ac] = w;
            // DMA B(next): linear 1KB per instr from the (s+1) slab
            if (wid < 4) {                    // wave-uniform
                const bf16* bsrc = bgp + (s + 1) * (DDIM * 32);
                #pragma unroll
                for (int j = 0; j < 7; ++j)
                    async16(bsrc + j * 512, Bn + (wc * 7 + j) * 512);
            }
            // prefetch a-regs for k=(s+2)*32
            if (s + 2 < NSTEP) {              // uniform
                const int k2 = (s + 2) * 32;
                a0 = *(const f32x4*)(agp + k2);
                a1 = *(const f32x4*)(agp + k2 + 4);
            }
        }

        short8 af[4], bfr[7];
        #pragma unroll
        for (int mi = 0; mi < 4; ++mi)
            af[mi] = *(const short8*)&Ac[(wr * 64 + mi * 16 + m_) * 32 + kq * 8];
        #pragma unroll
        for (int ni = 0; ni < 7; ++ni)
            bfr[ni] = *(const short8*)&Bc[(wc * 112 + ni * 16 + m_) * 32 + kq * 8];

        #pragma unroll
        for (int mi = 0; mi < 4; ++mi)
            #pragma unroll
            for (int ni = 0; ni < 7; ++ni)
                acc[mi][ni] = __builtin_amdgcn_mfma_f32_16x16x32_bf16(
                    af[mi], bfr[ni], acc[mi][ni], 0, 0, 0);

        __syncthreads();   // cur fully read; next buffers + vmem drained
    }

    // ---- epilogue: 4 stages of 32 rows; padded LDS bounce (stride 452 f32)
    float* Cb = (float*)(smem + 16384);       // 32 x 452 fp32
    #pragma unroll
    for (int t = 0; t < 4; ++t) {
        if (wr == (t >> 1)) {                 // wave-uniform: row-half owners
            #pragma unroll
            for (int mi2 = 0; mi2 < 2; ++mi2) {
                const int mi = (t & 1) * 2 + mi2;
                #pragma unroll
                for (int ni = 0; ni < 7; ++ni) {
                    const int col = wc * 112 + ni * 16 + m_;
                    #pragma unroll
                    for (int r = 0; r < 4; ++r)
                        Cb[(mi2 * 16 + kq * 4 + r) * 452 + col] = acc[mi][ni][r];
                }
            }
        }
        __syncthreads();
        // flat coalesced readout: 32x448 f32 = 3584 vec4 = 7 x 512
        const f32x4* Cb4 = (const f32x4*)Cb;
        f32x4* dst4 = (f32x4*)(out + (row0 + t * 32) * DDIM);
        #pragma unroll
        for (int j = 0; j < 7; ++j) {
            const int v   = j * 512 + tid;
            const int row = v / 112;          // 112 vec4 per output row
            const int cw  = v - row * 112;
            dst4[v] = Cb4[row * 113 + cw];    // 113 vec4 = 452 f32 stride
        }
        __syncthreads();   // before next stage overwrites Cb
    }
}

// ---------------------------------------------------------------------------
extern "C" void kernel_launch(void* const* d_in, const int* in_sizes, int n_in,
                              void* d_out, int out_size, void* d_ws, size_t ws_size,
                              hipStream_t stream) {
    const float* x  = (const float*)d_in[0];
    const float* Wq = (const float*)d_in[1];
    const float* Wk = (const float*)d_in[2];
    const float* Wv = (const float*)d_in[3];
    const float* Wo = (const float*)d_in[4];
    const float* Ad = (const float*)d_in[5];
    const float* Bd = (const float*)d_in[6];
    const float* Cd = (const float*)d_in[7];

    bf16*  Wt  = (bf16*)d_ws;                      // 448*448*2 = 392 KiB scratch
    float* out = (float*)d_out;

    const int M = in_sizes[0] / DDIM;              // 32768

    prep_wc<<<dim3(7, 7), 256, 0, stream>>>(Wq, Wk, Wv, Wo, Ad, Bd, Cd, Wt);
    gemm_xwc<<<M / 128, 512, 0, stream>>>(x, Wt, out);
}

// Round 6
// 140.143 us; speedup vs baseline: 1.1230x; 1.0190x over previous
//
#include <hip/hip_runtime.h>
#include <hip/hip_bf16.h>

#define DDIM 448
#define NSTEP 14            // 448 / 32

typedef __hip_bfloat16 bf16;
typedef __attribute__((ext_vector_type(8))) short short8;   // 8 bf16 = 16B (MFMA A/B frag)
typedef __attribute__((ext_vector_type(4))) float f32x4;    // MFMA C/D frag / float4

__device__ __forceinline__ short bf_bits(float f) {
    bf16 h = __float2bfloat16(f);
    return *reinterpret_cast<short*>(&h);
}

// async global->LDS DMA: per-lane 16B; LDS dst = wave-uniform base + lane*16
__device__ __forceinline__ void async16(const bf16* g, bf16* l) {
    __builtin_amdgcn_global_load_lds(
        (const __attribute__((address_space(1))) void*)g,
        (__attribute__((address_space(3))) void*)l, 16, 0, 0);
}

// ---------------------------------------------------------------------------
// Kernel 1: fused weight  E[i][d] = Wq*diagA + Wk*diagB + Wv*diagC,
//           Wc[i][o] = sum_d E[i][d] * Wo[d][o].
// Output layout (verified): Wt[s][o][k] = Wc[s*32+k][o] — the GEMM's exact
// LDS image; each K-step slab is 448*32*2 = 28 KB contiguous so the GEMM's
// global_load_lds reads are 1 KB linear.  UNCHANGED.
// ---------------------------------------------------------------------------
__global__ __launch_bounds__(256) void prep_wc(
    const float* __restrict__ Wq, const float* __restrict__ Wk,
    const float* __restrict__ Wv, const float* __restrict__ Wo,
    const float* __restrict__ Ad, const float* __restrict__ Bd,
    const float* __restrict__ Cd, bf16* __restrict__ Wt)
{
    __shared__ __align__(16) bf16 As[64 * 32];
    __shared__ __align__(16) bf16 Bs[64 * 32];
    __shared__ float da[DDIM], db[DDIM], dc[DDIM];

    const int tid  = threadIdx.x;
    const int i0   = blockIdx.x * 64;
    const int o0   = blockIdx.y * 64;
    const int lane = tid & 63;
    const int wid  = tid >> 6;
    const int wm   = wid >> 1, wn = wid & 1;
    const int m_   = lane & 15, kq = lane >> 4;

    for (int d = tid; d < DDIM; d += 256) {
        da[d] = Ad[d * DDIM + d];
        db[d] = Bd[d * DDIM + d];
        dc[d] = Cd[d * DDIM + d];
    }

    const int dr  = tid >> 3;
    const int oc8 = (tid & 7) * 8;
    const int ir  = tid >> 2;
    const int dc8 = (tid & 3) * 8;

    f32x4 acc[2][2] = {};

    f32x4 w0 = *(const f32x4*)(Wo + dr * DDIM + o0 + oc8);
    f32x4 w1 = *(const f32x4*)(Wo + dr * DDIM + o0 + oc8 + 4);
    f32x4 q0 = *(const f32x4*)(Wq + (i0 + ir) * DDIM + dc8);
    f32x4 q1 = *(const f32x4*)(Wq + (i0 + ir) * DDIM + dc8 + 4);
    f32x4 t0 = *(const f32x4*)(Wk + (i0 + ir) * DDIM + dc8);
    f32x4 t1 = *(const f32x4*)(Wk + (i0 + ir) * DDIM + dc8 + 4);
    f32x4 v0 = *(const f32x4*)(Wv + (i0 + ir) * DDIM + dc8);
    f32x4 v1 = *(const f32x4*)(Wv + (i0 + ir) * DDIM + dc8 + 4);

    for (int k0 = 0; k0 < DDIM; k0 += 32) {
        __syncthreads();
        #pragma unroll
        for (int j = 0; j < 4; ++j) {
            As[(oc8 + j) * 32 + dr]     = __float2bfloat16(w0[j]);
            As[(oc8 + 4 + j) * 32 + dr] = __float2bfloat16(w1[j]);
        }
        short8 e;
        #pragma unroll
        for (int j = 0; j < 4; ++j) {
            e[j]     = bf_bits(q0[j] * da[k0 + dc8 + j]
                             + t0[j] * db[k0 + dc8 + j]
                             + v0[j] * dc[k0 + dc8 + j]);
            e[j + 4] = bf_bits(q1[j] * da[k0 + dc8 + 4 + j]
                             + t1[j] * db[k0 + dc8 + 4 + j]
                             + v1[j] * dc[k0 + dc8 + 4 + j]);
        }
        *(short8*)&Bs[ir * 32 + dc8] = e;
        __syncthreads();

        const int kn = (k0 + 32 < DDIM) ? k0 + 32 : 0;
        w0 = *(const f32x4*)(Wo + (kn + dr) * DDIM + o0 + oc8);
        w1 = *(const f32x4*)(Wo + (kn + dr) * DDIM + o0 + oc8 + 4);
        q0 = *(const f32x4*)(Wq + (i0 + ir) * DDIM + kn + dc8);
        q1 = *(const f32x4*)(Wq + (i0 + ir) * DDIM + kn + dc8 + 4);
        t0 = *(const f32x4*)(Wk + (i0 + ir) * DDIM + kn + dc8);
        t1 = *(const f32x4*)(Wk + (i0 + ir) * DDIM + kn + dc8 + 4);
        v0 = *(const f32x4*)(Wv + (i0 + ir) * DDIM + kn + dc8);
        v1 = *(const f32x4*)(Wv + (i0 + ir) * DDIM + kn + dc8 + 4);

        short8 af[2], bfr[2];
        #pragma unroll
        for (int mi = 0; mi < 2; ++mi)
            af[mi] = *(const short8*)&As[(wm * 32 + mi * 16 + m_) * 32 + kq * 8];
        #pragma unroll
        for (int ni = 0; ni < 2; ++ni)
            bfr[ni] = *(const short8*)&Bs[(wn * 32 + ni * 16 + m_) * 32 + kq * 8];
        #pragma unroll
        for (int mi = 0; mi < 2; ++mi)
            #pragma unroll
            for (int ni = 0; ni < 2; ++ni)
                acc[mi][ni] = __builtin_amdgcn_mfma_f32_16x16x32_bf16(
                    af[mi], bfr[ni], acc[mi][ni], 0, 0, 0);
    }

    #pragma unroll
    for (int mi = 0; mi < 2; ++mi)
        #pragma unroll
        for (int ni = 0; ni < 2; ++ni) {
            const int o = o0 + wm * 32 + mi * 16 + kq * 4;
            const int i = i0 + wn * 32 + ni * 16 + m_;
            bf16* dst = Wt + (i >> 5) * (DDIM * 32) + (i & 31);
            #pragma unroll
            for (int r = 0; r < 4; ++r)
                dst[(o + r) * 32] = __float2bfloat16(acc[mi][ni][r]);
        }
}

// ---------------------------------------------------------------------------
// Kernel 2: out[M x 448](fp32) = X(fp32) @ Wc.  B supplied as Wt[s][o][k].
// v6 (resubmitted — R5 failed on container infra, no kernel verdict):
// v5 (128x448 tile, 512 thr / 8 waves, linear 1KB B-DMA) with the barrier
// drain fixed (T3/T4):
//   * B is TRIPLE-buffered; DMA for step s+2 is issued at step s, so the
//     DMA waited on at the end of step s (B(s+1)) was issued a FULL STEP
//     earlier — its latency hides under step s's compute.
//   * End-of-step: s_waitcnt vmcnt(9) (retires B(s+1); leaves X(s+2) 2 +
//     B(s+2) 7 = 9 in flight ACROSS the raw s_barrier) + lgkmcnt(0).
//     v5's __syncthreads compiled to vmcnt(0): it drained the DMA issued
//     in the SAME step -> full latency exposed every step (step ~5100 cy
//     vs ~1000 cy of work; MfmaUtil 10, VALUBusy 5, HBM 26% = all idle).
//   * Count correctness (order-robust): at the wait, a DMA wave holds at
//     most {B(s+1) 7, X(s+2) 2, B(s+2) 7} = 16 outstanding; B(s+1) is
//     always the 7 oldest regardless of intra-step issue order, so
//     vmcnt(9) guarantees it retired. Waves 4-7 hold <=2 -> no-op wait
//     (no divergent barrier). Last 2 steps: vmcnt(0). NO sched_barrier.
//   * Buffer-reuse safety: DMA B(s+2) targets buf (s+2)%3, last read at
//     step s-1 and fenced by that step's lgkmcnt(0)+barrier.
// smem: A0 @0 (8K), A1 @8K, B @16K/44K/72K (3x28K) = 100 KB -> 1 block/CU.
// Epilogue Cb @16K: 32 x 452 x 4B (aliases B; all DMAs retired by then).
// ---------------------------------------------------------------------------
__global__ __launch_bounds__(512, 2) void gemm_xwc(
    const float* __restrict__ X, const bf16* __restrict__ Wt,
    float* __restrict__ out)
{
    __shared__ __align__(16) char smem[102400];         // 100 KB

    const int tid  = threadIdx.x;
    const int lane = tid & 63;
    const int wid  = tid >> 6;               // 0..7
    const int wr   = wid >> 2;               // row half: rows wr*64 + [0,64)
    const int wc   = wid & 3;                // col quarter: cols wc*112 + [0,112)
    const int m_   = lane & 15;
    const int kq   = lane >> 4;
    const int row0 = blockIdx.x * 128;

    // A staging: 128x32 fp32 -> 8 f32/thread
    const int ar = tid >> 2;                 // 0..127
    const int ac = (tid & 3) * 8;            // 0,8,16,24
    const float* agp = X + (row0 + ar) * DDIM + ac;

    // B DMA (waves 0-3): instr j moves 1 KB linear from the Wt slab
    const bf16* bgp = Wt + wc * 7 * 512 + lane * 8;

    f32x4 acc[4][7] = {};

    // ---- prologue -------------------------------------------------------
    // issue order: X(0) | stage A(0) | X(1) | DMA B(0) | DMA B(1)
    // wait vmcnt(7): newer-than-B(0) is at most {X(1) 2, B(1) 7} and B(0)
    // sits within the 9 oldest of <=16; 7 leaves B(1) (and maybe X(1)) in
    // flight while guaranteeing B(0) retired (over-wait at worst).
    f32x4 a0 = *(const f32x4*)(agp);
    f32x4 a1 = *(const f32x4*)(agp + 4);
    {
        bf16* A0 = (bf16*)smem;
        short8 w;
        #pragma unroll
        for (int j = 0; j < 4; ++j) {
            w[j] = bf_bits(a0[j]); w[j + 4] = bf_bits(a1[j]);
        }
        *(short8*)&A0[ar * 32 + ac] = w;     // byte addr = tid*16
    }
    a0 = *(const f32x4*)(agp + 32);          // X(1)
    a1 = *(const f32x4*)(agp + 36);
    if (wid < 4) {
        bf16* B0 = (bf16*)(smem + 16384);
        bf16* B1 = (bf16*)(smem + 16384 + 28672);
        #pragma unroll
        for (int j = 0; j < 7; ++j)
            async16(bgp + j * 512, B0 + (wc * 7 + j) * 512);
        const bf16* b1 = bgp + DDIM * 32;
        #pragma unroll
        for (int j = 0; j < 7; ++j)
            async16(b1 + j * 512, B1 + (wc * 7 + j) * 512);
    }
    asm volatile("s_waitcnt vmcnt(7)" ::: "memory");
    asm volatile("s_waitcnt lgkmcnt(0)" ::: "memory");
    __builtin_amdgcn_s_barrier();            // A(0)+B(0) ready; B(1) in flight

    int bcur = 0;                            // buf idx of B(s)
    int bn2  = 2;                            // buf idx of B(s+2)
    for (int s = 0; s < NSTEP; ++s) {
        const bf16* Ac = (const bf16*)(smem + ((s & 1) << 13));
        const bf16* Bc = (const bf16*)(smem + 16384 + bcur * 28672);

        // 1. stage A(s+1) from a-regs (loaded last step / prologue)
        if (s + 1 < NSTEP) {                  // uniform
            bf16* An = (bf16*)(smem + (((s + 1) & 1) << 13));
            short8 w;
            #pragma unroll
            for (int j = 0; j < 4; ++j) {
                w[j] = bf_bits(a0[j]); w[j + 4] = bf_bits(a1[j]);
            }
            *(short8*)&An[ar * 32 + ac] = w;
        }
        // 2. load X(s+2) a-regs
        if (s + 2 < NSTEP) {                  // uniform
            const int k2 = (s + 2) * 32;
            a0 = *(const f32x4*)(agp + k2);
            a1 = *(const f32x4*)(agp + k2 + 4);
        }
        // 3. DMA B(s+2) into buf (s+2)%3
        if (s + 2 < NSTEP && wid < 4) {       // wave-uniform
            bf16* Bn = (bf16*)(smem + 16384 + bn2 * 28672);
            const bf16* bsrc = bgp + (s + 2) * (DDIM * 32);
            #pragma unroll
            for (int j = 0; j < 7; ++j)
                async16(bsrc + j * 512, Bn + (wc * 7 + j) * 512);
        }

        // 4. fragments + MFMA on (A(s), B(s))
        short8 af[4], bfr[7];
        #pragma unroll
        for (int mi = 0; mi < 4; ++mi)
            af[mi] = *(const short8*)&Ac[(wr * 64 + mi * 16 + m_) * 32 + kq * 8];
        #pragma unroll
        for (int ni = 0; ni < 7; ++ni)
            bfr[ni] = *(const short8*)&Bc[(wc * 112 + ni * 16 + m_) * 32 + kq * 8];

        #pragma unroll
        for (int mi = 0; mi < 4; ++mi)
            #pragma unroll
            for (int ni = 0; ni < 7; ++ni)
                acc[mi][ni] = __builtin_amdgcn_mfma_f32_16x16x32_bf16(
                    af[mi], bfr[ni], acc[mi][ni], 0, 0, 0);

        // 5. counted wait: retire B(s+1) only; keep X(s+2)+B(s+2) in flight
        if (s < NSTEP - 2) {
            asm volatile("s_waitcnt vmcnt(9)" ::: "memory");
        } else {
            asm volatile("s_waitcnt vmcnt(0)" ::: "memory");
        }
        asm volatile("s_waitcnt lgkmcnt(0)" ::: "memory");
        __builtin_amdgcn_s_barrier();

        bcur = (bcur == 2) ? 0 : bcur + 1;
        bn2  = (bn2  == 2) ? 0 : bn2  + 1;
    }

    // ---- epilogue: 4 stages of 32 rows; padded LDS bounce (stride 452 f32)
    float* Cb = (float*)(smem + 16384);       // 32 x 452 fp32 (aliases B)
    #pragma unroll
    for (int t = 0; t < 4; ++t) {
        if (wr == (t >> 1)) {                 // wave-uniform: row-half owners
            #pragma unroll
            for (int mi2 = 0; mi2 < 2; ++mi2) {
                const int mi = (t & 1) * 2 + mi2;
                #pragma unroll
                for (int ni = 0; ni < 7; ++ni) {
                    const int col = wc * 112 + ni * 16 + m_;
                    #pragma unroll
                    for (int r = 0; r < 4; ++r)
                        Cb[(mi2 * 16 + kq * 4 + r) * 452 + col] = acc[mi][ni][r];
                }
            }
        }
        __syncthreads();
        // flat coalesced readout: 32x448 f32 = 3584 vec4 = 7 x 512
        const f32x4* Cb4 = (const f32x4*)Cb;
        f32x4* dst4 = (f32x4*)(out + (row0 + t * 32) * DDIM);
        #pragma unroll
        for (int j = 0; j < 7; ++j) {
            const int v   = j * 512 + tid;
            const int row = v / 112;          // 112 vec4 per output row
            const int cw  = v - row * 112;
            dst4[v] = Cb4[row * 113 + cw];    // 113 vec4 = 452 f32 stride
        }
        __syncthreads();   // before next stage overwrites Cb
    }
}

// ---------------------------------------------------------------------------
extern "C" void kernel_launch(void* const* d_in, const int* in_sizes, int n_in,
                              void* d_out, int out_size, void* d_ws, size_t ws_size,
                              hipStream_t stream) {
    const float* x  = (const float*)d_in[0];
    const float* Wq = (const float*)d_in[1];
    const float* Wk = (const float*)d_in[2];
    const float* Wv = (const float*)d_in[3];
    const float* Wo = (const float*)d_in[4];
    const float* Ad = (const float*)d_in[5];
    const float* Bd = (const float*)d_in[6];
    const float* Cd = (const float*)d_in[7];

    bf16*  Wt  = (bf16*)d_ws;                      // 448*448*2 = 392 KiB scratch
    float* out = (float*)d_out;

    const int M = in_sizes[0] / DDIM;              // 32768

    prep_wc<<<dim3(7, 7), 256, 0, stream>>>(Wq, Wk, Wv, Wo, Ad, Bd, Cd, Wt);
    gemm_xwc<<<M / 128, 512, 0, stream>>>(x, Wt, out);
}